// Round 1
// baseline (222.601 us; speedup 1.0000x reference)
//
#include <hip/hip_runtime.h>
#include <hip/hip_bf16.h>

// FNO 2D spectral conv, MI355X. B=8,H=256,W=256,CIN=COUT=32,M1=M2=16.
// Pipeline: twiddles -> w-DFT -> h-DFT -> channel mix -> h-IDFT -> w-IDFT(c2r).
// All f32 vector math (no fp32 MFMA on CDNA4). Twiddles rebuilt every launch
// (d_ws is re-poisoned by the harness before each call).

#define TWO_PI 6.283185307179586476925286766559

// ---------------------------------------------------------------- twiddles
__global__ void k_twiddle(float* __restrict__ E1, float* __restrict__ E2,
                          float* __restrict__ E3, float* __restrict__ E4) {
  int stride = gridDim.x * blockDim.x;
  int t0 = blockIdx.x * blockDim.x + threadIdx.x;
  // E1: [w 0..127][kw 0..15][2]  e^{-2pi i kw w/256}
  for (int i = t0; i < 128 * 16; i += stride) {
    int w = i >> 4, kw = i & 15;
    int m = (kw * w) & 255;
    double a = -TWO_PI * (double)m / 256.0;
    E1[2 * i] = (float)cos(a);
    E1[2 * i + 1] = (float)sin(a);
  }
  // E2: [kh 0..31][h 0..255][2]  e^{-2pi i kha h/256}, kha = kh<16?kh:kh+224
  // E3 = conj(E2)  (forward vs inverse over h)
  for (int i = t0; i < 32 * 256; i += stride) {
    int kh = i >> 8, h = i & 255;
    int kha = kh < 16 ? kh : kh + 224;
    int m = (kha * h) & 255;
    double a = -TWO_PI * (double)m / 256.0;
    float cc = (float)cos(a), ss = (float)sin(a);
    E2[2 * i] = cc; E2[2 * i + 1] = ss;
    E3[2 * i] = cc; E3[2 * i + 1] = -ss;
  }
  // E4: [w 0..127][kw 0..15][2]  (c_kw/65536) * e^{+2pi i kw w/256}, c_0=1 else 2
  for (int i = t0; i < 128 * 16; i += stride) {
    int w = i >> 4, kw = i & 15;
    int m = (kw * w) & 255;
    double a = TWO_PI * (double)m / 256.0;
    double s = (kw == 0 ? 1.0 : 2.0) / 65536.0;
    E4[2 * i] = (float)(s * cos(a));
    E4[2 * i + 1] = (float)(s * sin(a));
  }
}

// ------------------------------------------------- K1: w-DFT  x -> T
// block = (b,h) flat (2048 blocks). T layout [b*256+h][c][kw][2] (1024 f/row).
__global__ __launch_bounds__(256) void k_wdft(const float* __restrict__ x,
                                              const float* __restrict__ E1,
                                              float* __restrict__ T) {
  __shared__ __align__(16) float sx[8192];  // x[b,h,:,:] : [w][c]
  int bh = blockIdx.x;
  int t = threadIdx.x;
  {
    const float4* src = (const float4*)(x + (size_t)bh * 8192);
    float4* dst = (float4*)sx;
#pragma unroll
    for (int i = 0; i < 8; ++i) dst[t + 256 * i] = src[t + 256 * i];
  }
  __syncthreads();
  int c = t >> 3, kwp = t & 7;  // kw0 = 2*kwp (even), kw1 = 2*kwp+1 (odd)
  float ar = 0.f, ai = 0.f, br = 0.f, bi = 0.f;
  const float4* e1 = (const float4*)E1;  // [w][kwp] = (cos_e,sin_e,cos_o,sin_o)
#pragma unroll 4
  for (int w = 0; w < 128; ++w) {
    float xa = sx[w * 32 + c];
    float xb = sx[(w + 128) * 32 + c];
    float ye = xa + xb;  // feeds even kw
    float yo = xa - xb;  // feeds odd kw
    float4 e = e1[w * 8 + kwp];
    ar += ye * e.x; ai += ye * e.y;
    br += yo * e.z; bi += yo * e.w;
  }
  // offset floats = c*32 + kwp*4 = 4*t  -> one float4 store, fully coalesced
  ((float4*)(T + (size_t)bh * 1024))[t] = make_float4(ar, ai, br, bi);
}

// ------------------------------------------------- K2: h-DFT  T -> X
// block = (b,c) flat (256). X layout [b*32+c][kh 0..31][kw][2] (1024 f/row).
__global__ __launch_bounds__(256) void k_hdft(const float* __restrict__ T,
                                              const float* __restrict__ E2,
                                              float* __restrict__ X) {
  __shared__ __align__(16) float sT[8192];  // [h][kw][2]
  int b = blockIdx.x >> 5, c = blockIdx.x & 31;
  int t = threadIdx.x;
  {
    const float4* src =
        (const float4*)(T + (size_t)b * 262144 + (size_t)t * 1024 + c * 32);
    float4* dst = (float4*)(sT + t * 32);
#pragma unroll
    for (int i = 0; i < 8; ++i) dst[i] = src[i];
  }
  __syncthreads();
  int kw = t & 15, kh = t >> 4;  // kh and kh+16
  const float2* e2a = (const float2*)E2 + kh * 256;
  const float2* e2b = (const float2*)E2 + (kh + 16) * 256;
  float x0r = 0, x0i = 0, x1r = 0, x1i = 0;
#pragma unroll 4
  for (int h = 0; h < 256; ++h) {
    float2 tv = *(const float2*)(sT + h * 32 + kw * 2);
    float2 ea = e2a[h], eb = e2b[h];
    x0r += tv.x * ea.x - tv.y * ea.y;
    x0i += tv.x * ea.y + tv.y * ea.x;
    x1r += tv.x * eb.x - tv.y * eb.y;
    x1i += tv.x * eb.y + tv.y * eb.x;
  }
  float2* Xb = (float2*)(X + (size_t)blockIdx.x * 1024);
  Xb[kh * 16 + kw] = make_float2(x0r, x0i);
  Xb[(kh + 16) * 16 + kw] = make_float2(x1r, x1i);
}

// ------------------------------------------------- K3: channel mix  X -> Y
// block = (b,kh) flat (256). Y layout [b][o][kh][kw][2].
__global__ __launch_bounds__(256) void k_mix(const float* __restrict__ X,
                                             const float* __restrict__ wr,
                                             const float* __restrict__ wi,
                                             float* __restrict__ Y) {
  __shared__ __align__(16) float sX[1024];  // [i][kw][2]
  int b = blockIdx.x >> 5, kh = blockIdx.x & 31;
  int blk = kh >> 4, khl = kh & 15;
  int t = threadIdx.x;
  {
    int i = t >> 3, p = t & 7;
    ((float4*)sX)[t] =
        *(const float4*)(X + (size_t)(b * 32 + i) * 1024 + kh * 32 + p * 4);
  }
  __syncthreads();
  int kw = t & 15, o = t >> 4;  // o and o+16
  const float* wr0 = wr + (size_t)blk * 262144 + khl * 16 + kw;
  const float* wi0 = wi + (size_t)blk * 262144 + khl * 16 + kw;
  float y0r = 0, y0i = 0, y1r = 0, y1i = 0;
#pragma unroll 4
  for (int i = 0; i < 32; ++i) {
    float2 xv = *(const float2*)(sX + i * 32 + kw * 2);
    float a0 = wr0[i * 8192 + o * 256], b0 = wi0[i * 8192 + o * 256];
    float a1 = wr0[i * 8192 + (o + 16) * 256], b1 = wi0[i * 8192 + (o + 16) * 256];
    y0r += xv.x * a0 - xv.y * b0;
    y0i += xv.x * b0 + xv.y * a0;
    y1r += xv.x * a1 - xv.y * b1;
    y1i += xv.x * b1 + xv.y * a1;
  }
  float2* Yb = (float2*)(Y + (size_t)b * 32768);
  Yb[(o * 32 + kh) * 16 + kw] = make_float2(y0r, y0i);
  Yb[((o + 16) * 32 + kh) * 16 + kw] = make_float2(y1r, y1i);
}

// ------------------------------------------------- K4: h-IDFT  Y -> G
// block = (b,o) flat (256). G layout [b*256+h][o][kw][2] (1024 f per (b,h)).
__global__ __launch_bounds__(256) void k_hidft(const float* __restrict__ Y,
                                               const float* __restrict__ E3,
                                               float* __restrict__ G) {
  __shared__ __align__(16) float sY[1024];  // [kh][kw][2]
  int bo = blockIdx.x;
  int t = threadIdx.x;
  ((float4*)sY)[t] = ((const float4*)(Y + (size_t)bo * 1024))[t];
  __syncthreads();
  int b = bo >> 5, o = bo & 31;
  int h = t;
  float gr[16], gi[16];
#pragma unroll
  for (int q = 0; q < 16; ++q) { gr[q] = 0.f; gi[q] = 0.f; }
  const float2* e3 = (const float2*)E3;
  for (int kh = 0; kh < 32; ++kh) {
    float2 e = e3[kh * 256 + h];
#pragma unroll
    for (int q = 0; q < 16; ++q) {
      float2 yv = *(const float2*)(sY + kh * 32 + q * 2);
      gr[q] += yv.x * e.x - yv.y * e.y;
      gi[q] += yv.x * e.y + yv.y * e.x;
    }
  }
  float* gp = G + (((size_t)b * 256 + h) * 32 + o) * 32;
#pragma unroll
  for (int q = 0; q < 8; ++q)
    ((float4*)gp)[q] = make_float4(gr[2 * q], gi[2 * q], gr[2 * q + 1], gi[2 * q + 1]);
}

// ------------------------------------------------- K5: w-IDFT (c2r) G -> out
// block = (b,h) flat (2048). out layout [b][h][w][o] (channels_last).
__global__ __launch_bounds__(256) void k_widft(const float* __restrict__ G,
                                               const float* __restrict__ E4,
                                               float* __restrict__ out) {
  __shared__ float sG[32 * 33];  // [o][kw][2], row stride 33 to dodge conflicts
  int bh = blockIdx.x;
  int t = threadIdx.x;
  {
    float4 v = ((const float4*)(G + (size_t)bh * 1024))[t];
    int o = t >> 3, p = t & 7;
    float* d = sG + o * 33 + p * 4;
    d[0] = v.x; d[1] = v.y; d[2] = v.z; d[3] = v.w;
  }
  __syncthreads();
  int o = t & 31, wb = t >> 5;
  float g[32];
#pragma unroll
  for (int k = 0; k < 32; ++k) g[k] = sG[o * 33 + k];
  float* ob = out + (size_t)bh * 8192 + o;
  const float4* e4 = (const float4*)E4;  // [w][q] = (c_e*cos, c_e*sin, c_o*cos, c_o*sin)
  for (int j = 0; j < 16; ++j) {
    int w = wb * 16 + j;
    float se = 0.f, so = 0.f;
#pragma unroll
    for (int q = 0; q < 8; ++q) {
      float4 e = e4[w * 8 + q];
      se += g[4 * q] * e.x - g[4 * q + 1] * e.y;      // even kw = 2q
      so += g[4 * q + 2] * e.z - g[4 * q + 3] * e.w;  // odd  kw = 2q+1
    }
    ob[(size_t)w * 32] = se + so;          // out[b,h,w,o]
    ob[(size_t)(w + 128) * 32] = se - so;  // out[b,h,w+128,o] (radix-2 fold)
  }
}

extern "C" void kernel_launch(void* const* d_in, const int* in_sizes, int n_in,
                              void* d_out, int out_size, void* d_ws, size_t ws_size,
                              hipStream_t stream) {
  const float* x = (const float*)d_in[0];   // [8,256,256,32]
  const float* wr = (const float*)d_in[1];  // [2,32,32,16,16]
  const float* wi = (const float*)d_in[2];
  float* out = (float*)d_out;               // [8,256,256,32]
  float* ws = (float*)d_ws;

  float* E1 = ws;             // 4096 f
  float* E2 = ws + 4096;      // 16384 f
  float* E3 = ws + 20480;     // 16384 f
  float* E4 = ws + 36864;     // 4096 f
  float* T  = ws + 40960;     // 2097152 f  [bh][c][kw][2]
  float* X  = ws + 2138112;   // 262144 f   [b*32+c][kh][kw][2]
  float* Y  = ws + 2400256;   // 262144 f   [b][o][kh][kw][2]
  float* G  = T;              // reuse T's space (T dead after K2)

  k_twiddle<<<64, 256, 0, stream>>>(E1, E2, E3, E4);
  k_wdft<<<2048, 256, 0, stream>>>(x, E1, T);
  k_hdft<<<256, 256, 0, stream>>>(T, E2, X);
  k_mix<<<256, 256, 0, stream>>>(X, wr, wi, Y);
  k_hidft<<<256, 256, 0, stream>>>(Y, E3, G);
  k_widft<<<2048, 256, 0, stream>>>(G, E4, out);
}

// Round 2
// 158.976 us; speedup vs baseline: 1.4002x; 1.4002x over previous
//
#include <hip/hip_runtime.h>
#include <math.h>

// FNO 2D spectral conv, MI355X. B=8,H=256,W=256,CIN=COUT=32,M1=M2=16.
// R2: LDS-staged twiddles, ds_read_b128 inner loops, radix-2 over h both ways,
// regridded middle kernels for occupancy, f32 twiddle gen.

#define INV_HW (1.0f / 65536.0f)

// ------------------------------------------------------------- twiddle gen
// E1: [w<128][kwp<8] float4 (cos_e,-sin_e,cos_o,-sin_o), theta = 2pi*m/256, kw_e=2kwp
// U : [n<256] float2 (cos, sin) of +2pi*n/256
// E4: [w<128][q<8] float4 (sc_e*cos_e, sc_e*sin_e, sc_o*cos_o, sc_o*sin_o), +angle
__global__ void k_tw(float* __restrict__ E1, float* __restrict__ U,
                     float* __restrict__ E4) {
  int t = blockIdx.x * blockDim.x + threadIdx.x;
  const float step = 6.28318530717958647692f / 256.0f;
  if (t < 1024) {
    int w = t >> 3, kwp = t & 7;
    int me = (2 * kwp * w) & 255, mo = ((2 * kwp + 1) * w) & 255;
    float se, ce, so, co;
    sincosf(step * (float)me, &se, &ce);
    sincosf(step * (float)mo, &so, &co);
    ((float4*)E1)[t] = make_float4(ce, -se, co, -so);
  } else if (t < 1280) {
    int n = t - 1024;
    float s, c;
    sincosf(step * (float)n, &s, &c);
    ((float2*)U)[n] = make_float2(c, s);
  } else if (t < 2304) {
    int i = t - 1280;
    int w = i >> 3, q = i & 7;
    int me = (2 * q * w) & 255, mo = ((2 * q + 1) * w) & 255;
    float se, ce, so, co;
    sincosf(step * (float)me, &se, &ce);
    sincosf(step * (float)mo, &so, &co);
    float sc_e = (q == 0) ? INV_HW : 2.0f * INV_HW;
    float sc_o = 2.0f * INV_HW;
    ((float4*)E4)[i] = make_float4(sc_e * ce, sc_e * se, sc_o * co, sc_o * so);
  }
}

// ------------------------------------------------- K1: w-DFT  x -> T
// block=(b,h) 2048. T layout [bh][c][kw][2]. sx transposed [c][260] for b128.
__global__ __launch_bounds__(256) void k_wdft(const float* __restrict__ x,
                                              const float* __restrict__ E1,
                                              float* __restrict__ T) {
  __shared__ __align__(16) float sx[32 * 260];  // 33.3 KB
  __shared__ float4 sE[1024];                   // 16 KB
  int bh = blockIdx.x, t = threadIdx.x;
  const float4* e1g = (const float4*)E1;
#pragma unroll
  for (int i = 0; i < 4; ++i) sE[t + 256 * i] = e1g[t + 256 * i];
  const float4* src = (const float4*)(x + (size_t)bh * 8192);
#pragma unroll
  for (int i = 0; i < 8; ++i) {
    int j = t + 256 * i;
    float4 v = src[j];
    int w = j >> 3, c0 = (j & 7) * 4;
    sx[(c0 + 0) * 260 + w] = v.x;
    sx[(c0 + 1) * 260 + w] = v.y;
    sx[(c0 + 2) * 260 + w] = v.z;
    sx[(c0 + 3) * 260 + w] = v.w;
  }
  __syncthreads();
  int c = t >> 3, kwp = t & 7;
  const float* xr = sx + c * 260;
  const float4* eb = sE + kwp;
  float ar = 0, ai = 0, br = 0, bi = 0;
#pragma unroll 4
  for (int j = 0; j < 32; ++j) {
    float4 xa = *(const float4*)(xr + 4 * j);
    float4 xb = *(const float4*)(xr + 128 + 4 * j);
    float4 e0 = eb[(4 * j + 0) * 8];
    float4 e1 = eb[(4 * j + 1) * 8];
    float4 e2 = eb[(4 * j + 2) * 8];
    float4 e3 = eb[(4 * j + 3) * 8];
    float ye, yo;
    ye = xa.x + xb.x; yo = xa.x - xb.x;
    ar += ye * e0.x; ai += ye * e0.y; br += yo * e0.z; bi += yo * e0.w;
    ye = xa.y + xb.y; yo = xa.y - xb.y;
    ar += ye * e1.x; ai += ye * e1.y; br += yo * e1.z; bi += yo * e1.w;
    ye = xa.z + xb.z; yo = xa.z - xb.z;
    ar += ye * e2.x; ai += ye * e2.y; br += yo * e2.z; bi += yo * e2.w;
    ye = xa.w + xb.w; yo = xa.w - xb.w;
    ar += ye * e3.x; ai += ye * e3.y; br += yo * e3.z; bi += yo * e3.w;
  }
  // float offset c*32 + kwp*4 = 4t -> one coalesced float4
  ((float4*)(T + (size_t)bh * 1024))[t] = make_float4(ar, ai, br, bi);
}

// ------------------------------------------------- K2: h-DFT  T -> X
// block=(b,c) 256 x 512 thr. Radix-2 over h; split-h partials + LDS reduce.
__global__ __launch_bounds__(512) void k_hdft(const float* __restrict__ T,
                                              const float* __restrict__ U,
                                              float* __restrict__ X) {
  __shared__ __align__(16) float sT[8192];  // [h][kw][2] 32 KB
  __shared__ float2 sU[256];
  __shared__ float4 sRed[256];
  int b = blockIdx.x >> 5, c = blockIdx.x & 31;
  int t = threadIdx.x;
  const float4* src = (const float4*)(T + (size_t)b * 262144 + c * 32);
  float4* dT = (float4*)sT;
#pragma unroll
  for (int i = 0; i < 4; ++i) {
    int j = t + 512 * i;
    dT[j] = src[(j >> 3) * 256 + (j & 7)];
  }
  if (t < 256) sU[t] = ((const float2*)U)[t];
  __syncthreads();
  int kw = t & 15, kh = (t >> 4) & 15, s = t >> 8;
  float sg = (kh & 1) ? -1.f : 1.f;  // (-1)^kha, kha parity == kh parity
  int st1 = kh, st2 = (kh + 240) & 255;
  int ph1 = (st1 * (s * 64)) & 255;
  int ph2 = (st2 * (s * 64)) & 255;
  float x0r = 0, x0i = 0, x1r = 0, x1i = 0;
  int h0 = s * 64;
#pragma unroll 4
  for (int hh = 0; hh < 64; ++hh) {
    int h = h0 + hh;
    float2 t0 = *(const float2*)(sT + h * 32 + kw * 2);
    float2 t1 = *(const float2*)(sT + (h + 128) * 32 + kw * 2);
    float tpx = fmaf(sg, t1.x, t0.x);
    float tpy = fmaf(sg, t1.y, t0.y);
    float2 e1 = sU[ph1];
    float2 e2 = sU[ph2];
    // (tp) * e^{-i theta} = (tpx*c + tpy*s) + i(tpy*c - tpx*s)
    x0r += tpx * e1.x + tpy * e1.y;
    x0i += tpy * e1.x - tpx * e1.y;
    x1r += tpx * e2.x + tpy * e2.y;
    x1i += tpy * e2.x - tpx * e2.y;
    ph1 = (ph1 + st1) & 255;
    ph2 = (ph2 + st2) & 255;
  }
  if (s == 1) sRed[t - 256] = make_float4(x0r, x0i, x1r, x1i);
  __syncthreads();
  if (s == 0) {
    float4 p = sRed[t];
    x0r += p.x; x0i += p.y; x1r += p.z; x1i += p.w;
    float2* Xb = (float2*)(X + (size_t)blockIdx.x * 1024);
    Xb[kh * 16 + kw] = make_float2(x0r, x0i);          // kha = kh
    Xb[(kh + 16) * 16 + kw] = make_float2(x1r, x1i);   // kha = kh+240
  }
}

// ------------------------------------------------- K3: channel mix  X -> Y
__global__ __launch_bounds__(256) void k_mix(const float* __restrict__ X,
                                             const float* __restrict__ wr,
                                             const float* __restrict__ wi,
                                             float* __restrict__ Y) {
  __shared__ __align__(16) float sX[1024];  // [i][kw][2]
  int b = blockIdx.x >> 5, kh = blockIdx.x & 31;
  int blk = kh >> 4, khl = kh & 15;
  int t = threadIdx.x;
  {
    int i = t >> 3, p = t & 7;
    ((float4*)sX)[t] =
        *(const float4*)(X + (size_t)(b * 32 + i) * 1024 + kh * 32 + p * 4);
  }
  __syncthreads();
  int kw = t & 15, o = t >> 4;  // o and o+16
  const float* wr0 = wr + (size_t)blk * 262144 + khl * 16 + kw;
  const float* wi0 = wi + (size_t)blk * 262144 + khl * 16 + kw;
  float y0r = 0, y0i = 0, y1r = 0, y1i = 0;
#pragma unroll 4
  for (int i = 0; i < 32; ++i) {
    float2 xv = *(const float2*)(sX + i * 32 + kw * 2);
    float a0 = wr0[i * 8192 + o * 256], b0 = wi0[i * 8192 + o * 256];
    float a1 = wr0[i * 8192 + (o + 16) * 256], b1 = wi0[i * 8192 + (o + 16) * 256];
    y0r += xv.x * a0 - xv.y * b0;
    y0i += xv.x * b0 + xv.y * a0;
    y1r += xv.x * a1 - xv.y * b1;
    y1i += xv.x * b1 + xv.y * a1;
  }
  float2* Yb = (float2*)(Y + (size_t)b * 32768);
  Yb[(o * 32 + kh) * 16 + kw] = make_float2(y0r, y0i);
  Yb[((o + 16) * 32 + kh) * 16 + kw] = make_float2(y1r, y1i);
}

// ------------------------------------------------- K4: h-IDFT  Y -> G
// grid (b,o,hc) = 1024, 256 thr: q=t&7 (kw pair), hl=t>>3. Radix-2: h & h+128.
__global__ __launch_bounds__(256) void k_hidft(const float* __restrict__ Y,
                                               const float* __restrict__ U,
                                               float* __restrict__ G) {
  __shared__ __align__(16) float4 sY4[256];  // [kh][kwpair] 4 KB
  __shared__ float2 sU[256];
  int bi = blockIdx.x;
  int b = bi >> 7, o = (bi >> 2) & 31, hc = bi & 3;
  int t = threadIdx.x;
  sY4[t] = ((const float4*)(Y + (size_t)(b * 32 + o) * 1024))[t];
  sU[t] = ((const float2*)U)[t];
  __syncthreads();
  int q = t & 7, hl = t >> 3;
  int h = hc * 32 + hl;
  float se0r = 0, se0i = 0, se1r = 0, se1i = 0;
  float so0r = 0, so0i = 0, so1r = 0, so1i = 0;
#pragma unroll 4
  for (int kh2 = 0; kh2 < 16; ++kh2) {
    int khe = 2 * kh2, kho = khe + 1;
    int khae = khe < 16 ? khe : khe + 224;
    int khao = kho < 16 ? kho : kho + 224;
    float2 ee = sU[(khae * h) & 255];
    float2 eo = sU[(khao * h) & 255];
    float4 yE = sY4[khe * 8 + q];
    float4 yO = sY4[kho * 8 + q];
    // y * e^{+i theta}
    se0r += yE.x * ee.x - yE.y * ee.y;
    se0i += yE.x * ee.y + yE.y * ee.x;
    se1r += yE.z * ee.x - yE.w * ee.y;
    se1i += yE.z * ee.y + yE.w * ee.x;
    so0r += yO.x * eo.x - yO.y * eo.y;
    so0i += yO.x * eo.y + yO.y * eo.x;
    so1r += yO.z * eo.x - yO.w * eo.y;
    so1i += yO.z * eo.y + yO.w * eo.x;
  }
  float* g0 = G + (((size_t)b * 256 + h) * 32 + o) * 32 + 4 * q;
  float* g1 = G + (((size_t)b * 256 + h + 128) * 32 + o) * 32 + 4 * q;
  *(float4*)g0 = make_float4(se0r + so0r, se0i + so0i, se1r + so1r, se1i + so1i);
  *(float4*)g1 = make_float4(se0r - so0r, se0i - so0i, se1r - so1r, se1i - so1i);
}

// ------------------------------------------------- K5: w-IDFT (c2r) G -> out
__global__ __launch_bounds__(256) void k_widft(const float* __restrict__ G,
                                               const float* __restrict__ E4,
                                               float* __restrict__ out) {
  __shared__ float sG[32 * 33];
  __shared__ float4 sE4[1024];  // 16 KB
  int bh = blockIdx.x, t = threadIdx.x;
  const float4* e4g = (const float4*)E4;
#pragma unroll
  for (int i = 0; i < 4; ++i) sE4[t + 256 * i] = e4g[t + 256 * i];
  {
    float4 v = ((const float4*)(G + (size_t)bh * 1024))[t];
    int o = t >> 3, p = t & 7;
    float* d = sG + o * 33 + p * 4;
    d[0] = v.x; d[1] = v.y; d[2] = v.z; d[3] = v.w;
  }
  __syncthreads();
  int o = t & 31, wb = t >> 5;
  float g[32];
#pragma unroll
  for (int k = 0; k < 32; ++k) g[k] = sG[o * 33 + k];
  float* ob = out + (size_t)bh * 8192 + o;
#pragma unroll 2
  for (int j = 0; j < 16; ++j) {
    int w = wb * 16 + j;
    float se = 0.f, so = 0.f;
#pragma unroll
    for (int q = 0; q < 8; ++q) {
      float4 e = sE4[w * 8 + q];
      se += g[4 * q] * e.x - g[4 * q + 1] * e.y;
      so += g[4 * q + 2] * e.z - g[4 * q + 3] * e.w;
    }
    ob[(size_t)w * 32] = se + so;
    ob[(size_t)(w + 128) * 32] = se - so;
  }
}

extern "C" void kernel_launch(void* const* d_in, const int* in_sizes, int n_in,
                              void* d_out, int out_size, void* d_ws, size_t ws_size,
                              hipStream_t stream) {
  const float* x = (const float*)d_in[0];   // [8,256,256,32]
  const float* wr = (const float*)d_in[1];  // [2,32,32,16,16]
  const float* wi = (const float*)d_in[2];
  float* out = (float*)d_out;               // [8,256,256,32]
  float* ws = (float*)d_ws;

  float* E1 = ws;            // 4096 f
  float* U  = ws + 4096;     // 512 f
  float* E4 = ws + 4608;     // 4096 f
  float* T  = ws + 8704;     // 2097152 f  [bh][c][kw][2]
  float* X  = ws + 2105856;  // 262144 f   [b*32+c][kh][kw][2]
  float* Y  = ws + 2368000;  // 262144 f   [b][o][kh][kw][2]
  float* G  = T;             // reuse (T dead after K2)

  k_tw<<<9, 256, 0, stream>>>(E1, U, E4);
  k_wdft<<<2048, 256, 0, stream>>>(x, E1, T);
  k_hdft<<<256, 512, 0, stream>>>(T, U, X);
  k_mix<<<256, 256, 0, stream>>>(X, wr, wi, Y);
  k_hidft<<<1024, 256, 0, stream>>>(Y, U, G);
  k_widft<<<2048, 256, 0, stream>>>(G, E4, out);
}